// Round 1
// baseline (3177.597 us; speedup 1.0000x reference)
//
#include <hip/hip_runtime.h>

typedef unsigned int u32;
typedef unsigned long long u64;
typedef unsigned char u8;

#define NB 4
#define T_ANCH 261120
#define NCAND 2048          // candidates per image (4 levels x 512)
#define KSEL 512
#define POSTN 512
#define LOG_MAXF 4.135166556742356f
#define NMS_TH 0.7f
#define LVL_OFF_F 8192.0f

__device__ __forceinline__ u32 mono32(float f){
  u32 u = __float_as_uint(f);
  return (u & 0x80000000u) ? ~u : (u | 0x80000000u);
}
__device__ __forceinline__ int lvl_hw(int lvl){ return 65536 >> (2*lvl); }
__device__ __forceinline__ int lvl_off(int lvl){
  // cumulative anchor offsets per level
  return (lvl>0?196608:0) + (lvl>1?49152:0) + (lvl>2?12288:0);
}

// ---------------------------------------------------------------------------
// K1: exact top-512 per (image, level) by (objectness desc, index asc).
// One block per (b,lvl). 64-iteration binary search on the 64-bit key
// (mono(value)<<32 | ~j)  -> exact 512th-largest key, then collect.
// ---------------------------------------------------------------------------
__global__ __launch_bounds__(1024) void k1_topk(
    const float* __restrict__ o0, const float* __restrict__ o1,
    const float* __restrict__ o2, const float* __restrict__ o3,
    int* __restrict__ cand_j)
{
  int bid = blockIdx.x;
  int b = bid >> 2, lvl = bid & 3;
  const float* ob = (lvl==0)?o0 : (lvl==1)?o1 : (lvl==2)?o2 : o3;
  int hw = lvl_hw(lvl);
  int size = 3*hw;
  const float* base = ob + (size_t)b*3*hw;

  __shared__ u64 s_lo, s_hi;
  __shared__ u32 s_wred[16];
  __shared__ int s_cnt;
  if (threadIdx.x == 0){ s_lo = 0ull; s_hi = ~0ull; s_cnt = 0; }
  __syncthreads();

  for (;;){
    u64 lo = s_lo, hi = s_hi;
    if (lo >= hi) break;
    u64 mid = lo + ((hi - lo) >> 1) + 1ull;
    u32 c = 0;
    for (int j = threadIdx.x; j < size; j += 1024){
      u32 pix = (u32)j / 3u;
      u32 a = (u32)j - pix*3u;
      float v = base[(size_t)a*hw + pix];
      u64 key = ((u64)mono32(v) << 32) | (u32)(~(u32)j);
      c += (key >= mid) ? 1u : 0u;
    }
    #pragma unroll
    for (int off = 32; off > 0; off >>= 1) c += __shfl_down(c, off, 64);
    if ((threadIdx.x & 63) == 0) s_wred[threadIdx.x >> 6] = c;
    __syncthreads();
    if (threadIdx.x == 0){
      u32 tot = 0;
      for (int w2 = 0; w2 < 16; ++w2) tot += s_wred[w2];
      if (tot >= (u32)KSEL) s_lo = mid; else s_hi = mid - 1ull;
    }
    __syncthreads();
  }
  u64 thr = s_lo;   // == exact 512th largest key
  for (int j = threadIdx.x; j < size; j += 1024){
    u32 pix = (u32)j / 3u;
    u32 a = (u32)j - pix*3u;
    float v = base[(size_t)a*hw + pix];
    u64 key = ((u64)mono32(v) << 32) | (u32)(~(u32)j);
    if (key >= thr){
      int slot = atomicAdd(&s_cnt, 1);
      if (slot < KSEL) cand_j[bid*KSEL + slot] = j;
    }
  }
}

// ---------------------------------------------------------------------------
// K2: decode the 8192 selected candidates; build sort keys.
// ---------------------------------------------------------------------------
__global__ __launch_bounds__(256) void k2_decode(
    const float* __restrict__ o0, const float* __restrict__ o1,
    const float* __restrict__ o2, const float* __restrict__ o3,
    const float* __restrict__ d0, const float* __restrict__ d1,
    const float* __restrict__ d2, const float* __restrict__ d3,
    const float* __restrict__ anchors,
    const int* __restrict__ cand_j,
    float* __restrict__ cscore, u32* __restrict__ csmono,
    u64* __restrict__ ctb, float* __restrict__ cbox, u8* __restrict__ cvalid)
{
  int c = blockIdx.x*256 + threadIdx.x;
  if (c >= NB*NCAND) return;
  int pair = c >> 9;          // (b,lvl) pair index
  int b = pair >> 2, lvl = pair & 3;
  int j = cand_j[c];
  int hw = lvl_hw(lvl);
  u32 pix = (u32)j / 3u;
  u32 a = (u32)j - pix*3u;
  const float* ob = (lvl==0)?o0 : (lvl==1)?o1 : (lvl==2)?o2 : o3;
  const float* dl = (lvl==0)?d0 : (lvl==1)?d1 : (lvl==2)?d2 : d3;

  float ov = ob[(size_t)(b*3 + (int)a)*hw + pix];
  size_t dbase = ((size_t)(b*3 + (int)a)*6)*(size_t)hw + pix;
  float dx  = dl[dbase + 0*(size_t)hw];
  float dy  = dl[dbase + 1*(size_t)hw];
  float dw  = dl[dbase + 2*(size_t)hw];
  float dh  = dl[dbase + 3*(size_t)hw];
  float dsn = dl[dbase + 4*(size_t)hw];
  float dcs = dl[dbase + 5*(size_t)hw];
  int t = lvl_off(lvl) + j;
  const float* an = anchors + ((size_t)b*T_ANCH + t)*5;
  float ax=an[0], ay=an[1], aw=an[2], ah=an[3], aa=an[4];
  dw = fminf(dw, LOG_MAXF); dh = fminf(dh, LOG_MAXF);
  float cx = ax + dx*aw;
  float cy = ay + dy*ah;
  float w  = aw * expf(dw);
  float h  = ah * expf(dh);
  float ang = aa + atan2f(dsn, dcs);
  double sd = 1.0 / (1.0 + exp(-(double)ov));
  float sc = (float)sd;
  bool valid = (w >= 1e-3f) && (h >= 1e-3f) && (sc >= 0.0f);
  cscore[c] = sc;
  csmono[c] = valid ? mono32(sc) : 0u;        // invalid => -inf (stable-sorted by tb)
  // tiebreak: level asc, obj desc, idx asc  (== reference positional order)
  ctb[c] = ((u64)lvl << 50) | ((u64)(u32)(~mono32(ov)) << 18) | (u64)(u32)j;
  cvalid[c] = valid ? 1 : 0;
  float* bb = cbox + (size_t)c*5;
  bb[0]=cx; bb[1]=cy; bb[2]=w; bb[3]=h; bb[4]=ang;
}

// ---------------------------------------------------------------------------
// K3: per-image stable-equivalent sort (score desc, tb asc) via bitonic in LDS,
// then gather sorted arrays + offset corners / AABB / area geometry.
// ---------------------------------------------------------------------------
__global__ __launch_bounds__(1024) void k3_sort(
    const u32* __restrict__ csmono, const u64* __restrict__ ctb,
    const float* __restrict__ cscore, const float* __restrict__ cbox,
    const u8* __restrict__ cvalid,
    float* __restrict__ sscore, float* __restrict__ sbox,
    float* __restrict__ geom, u8* __restrict__ svalid)
{
  int b = blockIdx.x;
  __shared__ u32 sm[NCAND];
  __shared__ u64 stb[NCAND];
  __shared__ u32 sid[NCAND];
  for (int k = threadIdx.x; k < NCAND; k += 1024){
    sm[k]  = csmono[b*NCAND + k];
    stb[k] = ctb[b*NCAND + k];
    sid[k] = (u32)k;
  }
  __syncthreads();
  for (int kk = 2; kk <= NCAND; kk <<= 1){
    for (int jj = kk >> 1; jj > 0; jj >>= 1){
      for (int i = threadIdx.x; i < NCAND; i += 1024){
        int ixj = i ^ jj;
        if (ixj > i){
          bool dirAsc = ((i & kk) == 0);
          u32 s1 = sm[i], s2 = sm[ixj];
          u64 t1 = stb[i], t2 = stb[ixj];
          bool before_ixj = (s2 > s1) || (s2 == s1 && t2 < t1);
          bool sw = dirAsc ? before_ixj : !before_ixj;
          if (sw){
            sm[i]=s2; sm[ixj]=s1;
            stb[i]=t2; stb[ixj]=t1;
            u32 tmp = sid[i]; sid[i]=sid[ixj]; sid[ixj]=tmp;
          }
        }
      }
      __syncthreads();
    }
  }
  for (int k = threadIdx.x; k < NCAND; k += 1024){
    int id = (int)sid[k];
    int gsrc = b*NCAND + id;
    int gdst = b*NCAND + k;
    float scv = cscore[gsrc];
    sscore[gdst] = scv;
    svalid[gdst] = cvalid[gsrc];
    float b0 = cbox[(size_t)gsrc*5+0], b1 = cbox[(size_t)gsrc*5+1];
    float b2 = cbox[(size_t)gsrc*5+2], b3 = cbox[(size_t)gsrc*5+3];
    float b4 = cbox[(size_t)gsrc*5+4];
    float* sb = sbox + (size_t)gdst*5;
    sb[0]=b0; sb[1]=b1; sb[2]=b2; sb[3]=b3; sb[4]=b4;
    int lvl = (int)((stb[k] >> 50) & 3ull);
    float offv = (float)lvl * LVL_OFF_F;
    float cx = b0 + offv, cy = b1 + offv, w=b2, h=b3, ang=b4;
    float cc = cosf(ang), sn = sinf(ang);
    float hx = 0.5f*w, hy = 0.5f*h;
    float x0 = cx + hx*cc - hy*sn, y0 = cy + hx*sn + hy*cc;
    float x1 = cx - hx*cc - hy*sn, y1 = cy - hx*sn + hy*cc;
    float x2 = cx - hx*cc + hy*sn, y2 = cy - hx*sn - hy*cc;
    float x3 = cx + hx*cc + hy*sn, y3 = cy + hx*sn - hy*cc;
    float minx = fminf(fminf(x0,x1),fminf(x2,x3));
    float maxx = fmaxf(fmaxf(x0,x1),fmaxf(x2,x3));
    float miny = fminf(fminf(y0,y1),fminf(y2,y3));
    float maxy = fmaxf(fmaxf(y0,y1),fmaxf(y2,y3));
    float* g = geom + (size_t)gdst*16;
    g[0]=minx; g[1]=maxx; g[2]=miny; g[3]=maxy; g[4]=w*h;
    g[5]=x0; g[6]=y0; g[7]=x1; g[8]=y1; g[9]=x2; g[10]=y2; g[11]=x3; g[12]=y3;
  }
}

// ---------------------------------------------------------------------------
// K4: rotated-IoU suppression mask. One lane per (i,j) pair, ballot -> word.
// Sutherland-Hodgman clip replicated from the reference (fully unrolled,
// constant indices -> registers only).
// ---------------------------------------------------------------------------
__device__ __forceinline__ void emit_pt(float* ox, float* oy, int oc, float x, float y){
  #pragma unroll
  for (int s = 0; s < 8; ++s) if (s == oc){ ox[s] = x; oy[s] = y; }
}

__device__ float quad_inter(const float* ca, const float* cb){
  float px[8], py[8];
  #pragma unroll
  for (int q = 0; q < 8; ++q){ px[q]=0.f; py[q]=0.f; }
  #pragma unroll
  for (int q = 0; q < 4; ++q){ px[q]=ca[2*q]; py[q]=ca[2*q+1]; }
  int cnt = 4;
  #pragma unroll
  for (int e = 0; e < 4; ++e){
    float p1x = cb[2*e],         p1y = cb[2*e+1];
    float p2x = cb[(2*e+2)&7],   p2y = cb[(2*e+3)&7];
    float ex = p2x-p1x, ey = p2y-p1y;
    float d[8];
    #pragma unroll
    for (int q = 0; q < 8; ++q) d[q] = ex*(py[q]-p1y) - ey*(px[q]-p1x);
    float ox[8], oy[8];
    #pragma unroll
    for (int q = 0; q < 8; ++q){ ox[q]=0.f; oy[q]=0.f; }
    int oc = 0;
    #pragma unroll
    for (int q = 0; q < 8; ++q){
      if (q < cnt){
        bool last = (q+1 >= cnt);
        float dn  = last ? d[0]  : d[(q+1)&7];
        bool in0 = (d[q] >= 0.0f), in1 = (dn >= 0.0f);
        if (in0){ emit_pt(ox,oy,oc,px[q],py[q]); oc++; }
        if (in0 != in1){
          float pnx = last ? px[0] : px[(q+1)&7];
          float pny = last ? py[0] : py[(q+1)&7];
          float den = d[q] - dn;
          float t = d[q] / ((den == 0.0f) ? 1.0f : den);
          emit_pt(ox,oy,oc, px[q] + t*(pnx-px[q]), py[q] + t*(pny-py[q]));
          oc++;
        }
      }
    }
    cnt = (oc > 8) ? 8 : oc;
    #pragma unroll
    for (int q = 0; q < 8; ++q){ px[q]=ox[q]; py[q]=oy[q]; }
  }
  if (cnt < 3) return 0.0f;
  float s = 0.0f;
  #pragma unroll
  for (int q = 0; q < 8; ++q){
    if (q < cnt){
      bool last = (q+1 >= cnt);
      float pnx = last ? px[0] : px[(q+1)&7];
      float pny = last ? py[0] : py[(q+1)&7];
      s += px[q]*pny - pnx*py[q];
    }
  }
  return 0.5f*fabsf(s);
}

__global__ __launch_bounds__(256) void k4_mask(
    const float* __restrict__ geom, u64* __restrict__ mask)
{
  int gt = blockIdx.x*256 + threadIdx.x;
  int img = gt >> 22;
  int rem = gt & ((1<<22)-1);
  int i = rem >> 11;
  int j = rem & (NCAND-1);
  bool bit = false;
  if (j > i){
    const float* gi = geom + ((size_t)(img*NCAND + i))*16;
    const float* gj = geom + ((size_t)(img*NCAND + j))*16;
    // AABB quick reject (decision-safe: disjoint => iou == 0)
    if (!(gi[0] > gj[1] || gj[0] > gi[1] || gi[2] > gj[3] || gj[2] > gi[3])){
      float inter = quad_inter(gi+5, gj+5);
      float iou = inter / (gi[4] + gj[4] - inter + 1e-7f);
      bit = (iou > NMS_TH);
    }
  }
  u64 bm = __ballot(bit);
  if ((threadIdx.x & 63) == 0)
    mask[((size_t)(img*NCAND + i))*32 + (j >> 6)] = bm;
}

// ---------------------------------------------------------------------------
// K5: sequential greedy suppression (bitmask walk), then ranked output.
// One block per image.
// ---------------------------------------------------------------------------
__global__ __launch_bounds__(1024) void k5_nms_out(
    const u64* __restrict__ mask, const u8* __restrict__ svalid,
    const float* __restrict__ sbox, const float* __restrict__ sscore,
    float* __restrict__ out)
{
  int b = blockIdx.x;
  __shared__ u64 sup[32];
  __shared__ u64 chunk[128*32];
  __shared__ u32 pref[32];
  if (threadIdx.x < 32){
    u64 w = 0;
    for (int t = 0; t < 64; ++t)
      if (!svalid[b*NCAND + threadIdx.x*64 + t]) w |= (1ull << t);
    sup[threadIdx.x] = w;               // invalid boxes start suppressed
  }
  __syncthreads();
  for (int cch = 0; cch < 16; ++cch){
    const u64* src = mask + ((size_t)(b*NCAND + cch*128))*32;
    for (int x = threadIdx.x; x < 128*32; x += 1024) chunk[x] = src[x];
    __syncthreads();
    if (threadIdx.x < 32){              // single-wave sequential walk
      for (int r = 0; r < 128; ++r){
        int gi = cch*128 + r;
        u64 sw = sup[gi >> 6];
        if (!((sw >> (gi & 63)) & 1ull))
          sup[threadIdx.x] |= chunk[r*32 + threadIdx.x];
      }
    }
    __syncthreads();
  }
  // zero-fill this image's output (d_out is poisoned before every launch)
  for (int x = threadIdx.x; x < POSTN*5; x += 1024) out[(size_t)b*POSTN*5 + x] = 0.0f;
  for (int x = threadIdx.x; x < POSTN;   x += 1024) out[(size_t)NB*POSTN*5 + b*POSTN + x] = 0.0f;
  if (threadIdx.x < 32) pref[threadIdx.x] = (u32)__popcll(~sup[threadIdx.x]);
  __syncthreads();
  if (threadIdx.x == 0){
    u32 run = 0;
    for (int w = 0; w < 32; ++w){ u32 t = pref[w]; pref[w] = run; run += t; }
  }
  __syncthreads();
  for (int i = threadIdx.x; i < NCAND; i += 1024){
    u64 kw = ~sup[i >> 6];
    if ((kw >> (i & 63)) & 1ull){
      u32 rank = pref[i >> 6] + (u32)__popcll(kw & ((1ull << (i & 63)) - 1ull));
      if (rank < POSTN){
        const float* bp = sbox + ((size_t)(b*NCAND + i))*5;
        float* op = out + ((size_t)(b*POSTN + rank))*5;
        op[0]=bp[0]; op[1]=bp[1]; op[2]=bp[2]; op[3]=bp[3]; op[4]=bp[4];
        out[(size_t)NB*POSTN*5 + b*POSTN + rank] = sscore[b*NCAND + i];
      }
    }
  }
}

// ---------------------------------------------------------------------------
extern "C" void kernel_launch(void* const* d_in, const int* in_sizes, int n_in,
                              void* d_out, int out_size, void* d_ws, size_t ws_size,
                              hipStream_t stream)
{
  (void)out_size; (void)ws_size;
  const float *obj[4] = {nullptr,nullptr,nullptr,nullptr};
  const float *dlt[4] = {nullptr,nullptr,nullptr,nullptr};
  const float *anchors = nullptr;
  for (int i = 0; i < n_in; ++i){
    int s = in_sizes[i];
    const float* p = (const float*)d_in[i];
    switch (s){
      case 786432:  obj[0] = p; break;
      case 4718592: dlt[0] = p; break;
      case 196608:  obj[1] = p; break;
      case 1179648: dlt[1] = p; break;
      case 49152:   obj[2] = p; break;
      case 294912:  dlt[2] = p; break;
      case 12288:   obj[3] = p; break;
      case 73728:   dlt[3] = p; break;
      case 5222400: anchors = p; break;
      default: break;
    }
  }

  char* wsb = (char*)d_ws;
  size_t off = 0;
  auto alloc = [&](size_t bytes)->void*{
    size_t cur = (off + 255) & ~(size_t)255;
    off = cur + bytes;
    return (void*)(wsb + cur);
  };
  int*   cand_j = (int*)  alloc(16*KSEL*sizeof(int));
  float* cscore = (float*)alloc((size_t)NB*NCAND*sizeof(float));
  u32*   csmono = (u32*)  alloc((size_t)NB*NCAND*sizeof(u32));
  u64*   ctb    = (u64*)  alloc((size_t)NB*NCAND*sizeof(u64));
  float* cbox   = (float*)alloc((size_t)NB*NCAND*5*sizeof(float));
  u8*    cvalid = (u8*)   alloc((size_t)NB*NCAND);
  float* sscore = (float*)alloc((size_t)NB*NCAND*sizeof(float));
  float* sbox   = (float*)alloc((size_t)NB*NCAND*5*sizeof(float));
  u8*    svalid = (u8*)   alloc((size_t)NB*NCAND);
  float* geom   = (float*)alloc((size_t)NB*NCAND*16*sizeof(float));
  u64*   maskp  = (u64*)  alloc((size_t)NB*NCAND*32*sizeof(u64));

  hipLaunchKernelGGL(k1_topk, dim3(16), dim3(1024), 0, stream,
                     obj[0], obj[1], obj[2], obj[3], cand_j);
  hipLaunchKernelGGL(k2_decode, dim3(32), dim3(256), 0, stream,
                     obj[0], obj[1], obj[2], obj[3],
                     dlt[0], dlt[1], dlt[2], dlt[3],
                     anchors, cand_j, cscore, csmono, ctb, cbox, cvalid);
  hipLaunchKernelGGL(k3_sort, dim3(4), dim3(1024), 0, stream,
                     csmono, ctb, cscore, cbox, cvalid, sscore, sbox, geom, svalid);
  hipLaunchKernelGGL(k4_mask, dim3(65536), dim3(256), 0, stream, geom, maskp);
  hipLaunchKernelGGL(k5_nms_out, dim3(4), dim3(1024), 0, stream,
                     maskp, svalid, sbox, sscore, (float*)d_out);
}

// Round 4
// 511.388 us; speedup vs baseline: 6.2137x; 6.2137x over previous
//
#include <hip/hip_runtime.h>

typedef unsigned int u32;
typedef unsigned long long u64;
typedef unsigned char u8;

#define NB 4
#define T_ANCH 261120
#define NCAND 2048          // candidates per image (4 levels x 512)
#define KSEL 512
#define POSTN 512
#define LOG_MAXF 4.135166556742356f
#define NMS_TH 0.7f
#define LVL_OFF_F 8192.0f
#define BINS 4096           // top-12 bits of mono32
#define EQCAP 8192          // tie-bin capacity (expected ~300-700 occupants)

__device__ __forceinline__ u32 mono32(float f){
  u32 u = __float_as_uint(f);
  return (u & 0x80000000u) ? ~u : (u | 0x80000000u);
}
__device__ __forceinline__ int lvl_hw(int lvl){ return 65536 >> (2*lvl); }
__device__ __forceinline__ int lvl_off(int lvl){
  return (lvl>0?196608:0) + (lvl>1?49152:0) + (lvl>2?12288:0);
}

// ---------------------------------------------------------------------------
// K1: exact top-512 per (image, level) by key (mono(obj)<<32 | ~j) where j is
// the PERMUTED index (j = pix*3 + a, matching the reference's [B,A,H,W] ->
// [B,H*W*A] flatten; memory-linear index is L = a*hw + pix).
// One block per (b,lvl):
//   A) 4096-bin LDS histogram of mono>>20 (float4 streaming; value-only)
//   -- 64 coarse sums + serial thread-0 walk -> threshold bin b0, cntAbove
//   B) classify: bin>b0 -> direct emit (permuted j); bin==b0 -> LDS tie keys
//   -- O(n^2) rank-select on tie set: emit iff rank < k = 512-cntAbove.
// Keys distinct (distinct j) => exactly 512 emitted. Slot order irrelevant
// (k3 re-sorts with the full deterministic tiebreak).
// ---------------------------------------------------------------------------
__global__ __launch_bounds__(1024) void k1_topk(
    const float* __restrict__ o0, const float* __restrict__ o1,
    const float* __restrict__ o2, const float* __restrict__ o3,
    int* __restrict__ cand_j)
{
  int bid = blockIdx.x;
  int b = bid >> 2, lvl = bid & 3;
  const float* ob = (lvl==0)?o0 : (lvl==1)?o1 : (lvl==2)?o2 : o3;
  int hw = lvl_hw(lvl);
  int size = 3*hw;                       // 196608 / 49152 / 12288 / 3072
  const float* base = ob + (size_t)b*size;
  const float4* b4 = (const float4*)base;  // size % 4 == 0, 16B-aligned
  int n4 = size >> 2;

  __shared__ u32 hist[BINS];
  __shared__ u64 eqbuf[EQCAP];
  __shared__ u32 coarse[64];
  __shared__ u32 s_b0, s_cntAbove, s_eqn, s_emit;

  int t = threadIdx.x;

  for (int i = t; i < BINS; i += 1024) hist[i] = 0;
  if (t == 0){ s_eqn = 0; s_emit = 0; }
  __syncthreads();

  // ---- Pass A: histogram of top-12 bits (value-only; order-independent) ----
  for (int i = t; i < n4; i += 1024){
    float4 v = b4[i];
    atomicAdd(&hist[mono32(v.x) >> 20], 1u);
    atomicAdd(&hist[mono32(v.y) >> 20], 1u);
    atomicAdd(&hist[mono32(v.z) >> 20], 1u);
    atomicAdd(&hist[mono32(v.w) >> 20], 1u);
  }
  __syncthreads();

  // ---- Coarse sums, then serial two-level descending walk ----
  if (t < 64){
    u32 s = 0;
    for (int z = 0; z < 64; ++z) s += hist[t*64 + z];
    coarse[t] = s;
  }
  __syncthreads();
  if (t == 0){
    u32 acc = 0;
    int cb = 63;
    while (acc + coarse[cb] < (u32)KSEL){ acc += coarse[cb]; --cb; }
    int z = cb*64 + 63;
    while (acc + hist[z] < (u32)KSEL){ acc += hist[z]; --z; }
    s_b0 = (u32)z;          // bin containing the 512th-largest key
    s_cntAbove = acc;       // count of elements in bins > b0  (< 512)
  }
  __syncthreads();
  u32 b0v = s_b0, cA = s_cntAbove;

  // ---- Pass B: classify (emit PERMUTED index j = (pix+q)*3 + a) ----
  for (int i = t; i < n4; i += 1024){
    float4 v = b4[i];
    int L = i << 2;                 // linear base index (= a*hw + pix)
    int a = L / hw;                 // same for all 4 lanes (hw % 4 == 0)
    int pix = L - a*hw;
    int j0 = pix*3 + a;             // permuted index of element q is j0 + 3q
    u32 m0 = mono32(v.x), m1 = mono32(v.y), m2 = mono32(v.z), m3 = mono32(v.w);
    u32 bb0 = m0 >> 20, bb1 = m1 >> 20, bb2 = m2 >> 20, bb3 = m3 >> 20;
    if (bb0 > b0v){ u32 s = atomicAdd(&s_emit,1u); if (s < (u32)KSEL) cand_j[bid*KSEL+s] = j0; }
    else if (bb0 == b0v){ u32 s = atomicAdd(&s_eqn,1u); if (s < (u32)EQCAP) eqbuf[s] = ((u64)m0<<32) | (u32)(~(u32)j0); }
    if (bb1 > b0v){ u32 s = atomicAdd(&s_emit,1u); if (s < (u32)KSEL) cand_j[bid*KSEL+s] = j0+3; }
    else if (bb1 == b0v){ u32 s = atomicAdd(&s_eqn,1u); if (s < (u32)EQCAP) eqbuf[s] = ((u64)m1<<32) | (u32)(~(u32)(j0+3)); }
    if (bb2 > b0v){ u32 s = atomicAdd(&s_emit,1u); if (s < (u32)KSEL) cand_j[bid*KSEL+s] = j0+6; }
    else if (bb2 == b0v){ u32 s = atomicAdd(&s_eqn,1u); if (s < (u32)EQCAP) eqbuf[s] = ((u64)m2<<32) | (u32)(~(u32)(j0+6)); }
    if (bb3 > b0v){ u32 s = atomicAdd(&s_emit,1u); if (s < (u32)KSEL) cand_j[bid*KSEL+s] = j0+9; }
    else if (bb3 == b0v){ u32 s = atomicAdd(&s_eqn,1u); if (s < (u32)EQCAP) eqbuf[s] = ((u64)m3<<32) | (u32)(~(u32)(j0+9)); }
  }
  __syncthreads();

  // ---- Tie resolution: O(n^2) exact rank-select ----
  u32 n = s_eqn < (u32)EQCAP ? s_eqn : (u32)EQCAP;
  u32 k = (u32)KSEL - cA;                 // >= 1, <= 512
  for (u32 i = t; i < n; i += 1024){
    u64 ki = eqbuf[i];
    u32 r = 0;
    for (u32 mm = 0; mm < n; ++mm) r += (eqbuf[mm] > ki) ? 1u : 0u;
    if (r < k){
      u32 s = atomicAdd(&s_emit, 1u);
      if (s < (u32)KSEL) cand_j[bid*KSEL + s] = (int)(~(u32)ki);
    }
  }
}

// ---------------------------------------------------------------------------
// K2: decode the 8192 selected candidates; build sort keys.
// ---------------------------------------------------------------------------
__global__ __launch_bounds__(256) void k2_decode(
    const float* __restrict__ o0, const float* __restrict__ o1,
    const float* __restrict__ o2, const float* __restrict__ o3,
    const float* __restrict__ d0, const float* __restrict__ d1,
    const float* __restrict__ d2, const float* __restrict__ d3,
    const float* __restrict__ anchors,
    const int* __restrict__ cand_j,
    float* __restrict__ cscore, u32* __restrict__ csmono,
    u64* __restrict__ ctb, float* __restrict__ cbox, u8* __restrict__ cvalid)
{
  int c = blockIdx.x*256 + threadIdx.x;
  if (c >= NB*NCAND) return;
  int pair = c >> 9;          // (b,lvl) pair index
  int b = pair >> 2, lvl = pair & 3;
  int j = cand_j[c];
  int hw = lvl_hw(lvl);
  u32 pix = (u32)j / 3u;
  u32 a = (u32)j - pix*3u;
  const float* ob = (lvl==0)?o0 : (lvl==1)?o1 : (lvl==2)?o2 : o3;
  const float* dl = (lvl==0)?d0 : (lvl==1)?d1 : (lvl==2)?d2 : d3;

  float ov = ob[(size_t)(b*3 + (int)a)*hw + pix];
  size_t dbase = ((size_t)(b*3 + (int)a)*6)*(size_t)hw + pix;
  float dx  = dl[dbase + 0*(size_t)hw];
  float dy  = dl[dbase + 1*(size_t)hw];
  float dw  = dl[dbase + 2*(size_t)hw];
  float dh  = dl[dbase + 3*(size_t)hw];
  float dsn = dl[dbase + 4*(size_t)hw];
  float dcs = dl[dbase + 5*(size_t)hw];
  int tt = lvl_off(lvl) + j;
  const float* an = anchors + ((size_t)b*T_ANCH + tt)*5;
  float ax=an[0], ay=an[1], aw=an[2], ah=an[3], aa=an[4];
  dw = fminf(dw, LOG_MAXF); dh = fminf(dh, LOG_MAXF);
  float cx = ax + dx*aw;
  float cy = ay + dy*ah;
  float w  = aw * expf(dw);
  float h  = ah * expf(dh);
  float ang = aa + atan2f(dsn, dcs);
  double sd = 1.0 / (1.0 + exp(-(double)ov));
  float sc = (float)sd;
  bool valid = (w >= 1e-3f) && (h >= 1e-3f) && (sc >= 0.0f);
  cscore[c] = sc;
  csmono[c] = valid ? mono32(sc) : 0u;        // invalid => -inf (stable-sorted by tb)
  // tiebreak: level asc, obj desc, idx asc  (== reference positional order)
  ctb[c] = ((u64)lvl << 50) | ((u64)(u32)(~mono32(ov)) << 18) | (u64)(u32)j;
  cvalid[c] = valid ? 1 : 0;
  float* bb = cbox + (size_t)c*5;
  bb[0]=cx; bb[1]=cy; bb[2]=w; bb[3]=h; bb[4]=ang;
}

// ---------------------------------------------------------------------------
// K3: per-image stable-equivalent sort (score desc, tb asc) via bitonic in LDS,
// then gather sorted arrays + offset corners / AABB / area geometry.
// ---------------------------------------------------------------------------
__global__ __launch_bounds__(1024) void k3_sort(
    const u32* __restrict__ csmono, const u64* __restrict__ ctb,
    const float* __restrict__ cscore, const float* __restrict__ cbox,
    const u8* __restrict__ cvalid,
    float* __restrict__ sscore, float* __restrict__ sbox,
    float* __restrict__ geom, u8* __restrict__ svalid)
{
  int b = blockIdx.x;
  __shared__ u32 sm[NCAND];
  __shared__ u64 stb[NCAND];
  __shared__ u32 sid[NCAND];
  for (int k = threadIdx.x; k < NCAND; k += 1024){
    sm[k]  = csmono[b*NCAND + k];
    stb[k] = ctb[b*NCAND + k];
    sid[k] = (u32)k;
  }
  __syncthreads();
  for (int kk = 2; kk <= NCAND; kk <<= 1){
    for (int jj = kk >> 1; jj > 0; jj >>= 1){
      for (int i = threadIdx.x; i < NCAND; i += 1024){
        int ixj = i ^ jj;
        if (ixj > i){
          bool dirAsc = ((i & kk) == 0);
          u32 s1 = sm[i], s2 = sm[ixj];
          u64 t1 = stb[i], t2 = stb[ixj];
          bool before_ixj = (s2 > s1) || (s2 == s1 && t2 < t1);
          bool sw = dirAsc ? before_ixj : !before_ixj;
          if (sw){
            sm[i]=s2; sm[ixj]=s1;
            stb[i]=t2; stb[ixj]=t1;
            u32 tmp = sid[i]; sid[i]=sid[ixj]; sid[ixj]=tmp;
          }
        }
      }
      __syncthreads();
    }
  }
  for (int k = threadIdx.x; k < NCAND; k += 1024){
    int id = (int)sid[k];
    int gsrc = b*NCAND + id;
    int gdst = b*NCAND + k;
    float scv = cscore[gsrc];
    sscore[gdst] = scv;
    svalid[gdst] = cvalid[gsrc];
    float b0 = cbox[(size_t)gsrc*5+0], b1 = cbox[(size_t)gsrc*5+1];
    float b2 = cbox[(size_t)gsrc*5+2], b3 = cbox[(size_t)gsrc*5+3];
    float b4 = cbox[(size_t)gsrc*5+4];
    float* sb = sbox + (size_t)gdst*5;
    sb[0]=b0; sb[1]=b1; sb[2]=b2; sb[3]=b3; sb[4]=b4;
    int lvl = (int)((stb[k] >> 50) & 3ull);
    float offv = (float)lvl * LVL_OFF_F;
    float cx = b0 + offv, cy = b1 + offv, w=b2, h=b3, ang=b4;
    float cc = cosf(ang), sn = sinf(ang);
    float hx = 0.5f*w, hy = 0.5f*h;
    float x0 = cx + hx*cc - hy*sn, y0 = cy + hx*sn + hy*cc;
    float x1 = cx - hx*cc - hy*sn, y1 = cy - hx*sn + hy*cc;
    float x2 = cx - hx*cc + hy*sn, y2 = cy - hx*sn - hy*cc;
    float x3 = cx + hx*cc + hy*sn, y3 = cy + hx*sn - hy*cc;
    float minx = fminf(fminf(x0,x1),fminf(x2,x3));
    float maxx = fmaxf(fmaxf(x0,x1),fmaxf(x2,x3));
    float miny = fminf(fminf(y0,y1),fminf(y2,y3));
    float maxy = fmaxf(fmaxf(y0,y1),fmaxf(y2,y3));
    float* g = geom + (size_t)gdst*16;
    g[0]=minx; g[1]=maxx; g[2]=miny; g[3]=maxy; g[4]=w*h;
    g[5]=x0; g[6]=y0; g[7]=x1; g[8]=y1; g[9]=x2; g[10]=y2; g[11]=x3; g[12]=y3;
  }
}

// ---------------------------------------------------------------------------
// K4: rotated-IoU suppression mask. One lane per (i,j) pair, ballot -> word.
// ---------------------------------------------------------------------------
__device__ __forceinline__ void emit_pt(float* ox, float* oy, int oc, float x, float y){
  #pragma unroll
  for (int s = 0; s < 8; ++s) if (s == oc){ ox[s] = x; oy[s] = y; }
}

__device__ float quad_inter(const float* ca, const float* cb){
  float px[8], py[8];
  #pragma unroll
  for (int q = 0; q < 8; ++q){ px[q]=0.f; py[q]=0.f; }
  #pragma unroll
  for (int q = 0; q < 4; ++q){ px[q]=ca[2*q]; py[q]=ca[2*q+1]; }
  int cnt = 4;
  #pragma unroll
  for (int e = 0; e < 4; ++e){
    float p1x = cb[2*e],         p1y = cb[2*e+1];
    float p2x = cb[(2*e+2)&7],   p2y = cb[(2*e+3)&7];
    float ex = p2x-p1x, ey = p2y-p1y;
    float d[8];
    #pragma unroll
    for (int q = 0; q < 8; ++q) d[q] = ex*(py[q]-p1y) - ey*(px[q]-p1x);
    float ox[8], oy[8];
    #pragma unroll
    for (int q = 0; q < 8; ++q){ ox[q]=0.f; oy[q]=0.f; }
    int oc = 0;
    #pragma unroll
    for (int q = 0; q < 8; ++q){
      if (q < cnt){
        bool last = (q+1 >= cnt);
        float dn  = last ? d[0]  : d[(q+1)&7];
        bool in0 = (d[q] >= 0.0f), in1 = (dn >= 0.0f);
        if (in0){ emit_pt(ox,oy,oc,px[q],py[q]); oc++; }
        if (in0 != in1){
          float pnx = last ? px[0] : px[(q+1)&7];
          float pny = last ? py[0] : py[(q+1)&7];
          float den = d[q] - dn;
          float t = d[q] / ((den == 0.0f) ? 1.0f : den);
          emit_pt(ox,oy,oc, px[q] + t*(pnx-px[q]), py[q] + t*(pny-py[q]));
          oc++;
        }
      }
    }
    cnt = (oc > 8) ? 8 : oc;
    #pragma unroll
    for (int q = 0; q < 8; ++q){ px[q]=ox[q]; py[q]=oy[q]; }
  }
  if (cnt < 3) return 0.0f;
  float s = 0.0f;
  #pragma unroll
  for (int q = 0; q < 8; ++q){
    if (q < cnt){
      bool last = (q+1 >= cnt);
      float pnx = last ? px[0] : px[(q+1)&7];
      float pny = last ? py[0] : py[(q+1)&7];
      s += px[q]*pny - pnx*py[q];
    }
  }
  return 0.5f*fabsf(s);
}

__global__ __launch_bounds__(256) void k4_mask(
    const float* __restrict__ geom, u64* __restrict__ mask)
{
  int gt = blockIdx.x*256 + threadIdx.x;
  int img = gt >> 22;
  int rem = gt & ((1<<22)-1);
  int i = rem >> 11;
  int j = rem & (NCAND-1);
  bool bit = false;
  if (j > i){
    const float* gi = geom + ((size_t)(img*NCAND + i))*16;
    const float* gj = geom + ((size_t)(img*NCAND + j))*16;
    // AABB quick reject (decision-safe: disjoint => iou == 0)
    if (!(gi[0] > gj[1] || gj[0] > gi[1] || gi[2] > gj[3] || gj[2] > gi[3])){
      float inter = quad_inter(gi+5, gj+5);
      float iou = inter / (gi[4] + gj[4] - inter + 1e-7f);
      bit = (iou > NMS_TH);
    }
  }
  u64 bm = __ballot(bit);
  if ((threadIdx.x & 63) == 0)
    mask[((size_t)(img*NCAND + i))*32 + (j >> 6)] = bm;
}

// ---------------------------------------------------------------------------
// K5: sequential greedy suppression (bitmask walk), then ranked output.
// ---------------------------------------------------------------------------
__global__ __launch_bounds__(1024) void k5_nms_out(
    const u64* __restrict__ mask, const u8* __restrict__ svalid,
    const float* __restrict__ sbox, const float* __restrict__ sscore,
    float* __restrict__ out)
{
  int b = blockIdx.x;
  __shared__ u64 sup[32];
  __shared__ u64 chunk[128*32];
  __shared__ u32 pref[32];
  if (threadIdx.x < 32){
    u64 w = 0;
    for (int t = 0; t < 64; ++t)
      if (!svalid[b*NCAND + threadIdx.x*64 + t]) w |= (1ull << t);
    sup[threadIdx.x] = w;               // invalid boxes start suppressed
  }
  __syncthreads();
  for (int cch = 0; cch < 16; ++cch){
    const u64* src = mask + ((size_t)(b*NCAND + cch*128))*32;
    for (int x = threadIdx.x; x < 128*32; x += 1024) chunk[x] = src[x];
    __syncthreads();
    if (threadIdx.x < 32){              // single-wave sequential walk
      for (int r = 0; r < 128; ++r){
        int gi = cch*128 + r;
        u64 sw = sup[gi >> 6];
        if (!((sw >> (gi & 63)) & 1ull))
          sup[threadIdx.x] |= chunk[r*32 + threadIdx.x];
      }
    }
    __syncthreads();
  }
  // zero-fill this image's output (d_out is poisoned before every launch)
  for (int x = threadIdx.x; x < POSTN*5; x += 1024) out[(size_t)b*POSTN*5 + x] = 0.0f;
  for (int x = threadIdx.x; x < POSTN;   x += 1024) out[(size_t)NB*POSTN*5 + b*POSTN + x] = 0.0f;
  if (threadIdx.x < 32) pref[threadIdx.x] = (u32)__popcll(~sup[threadIdx.x]);
  __syncthreads();
  if (threadIdx.x == 0){
    u32 run = 0;
    for (int w = 0; w < 32; ++w){ u32 t = pref[w]; pref[w] = run; run += t; }
  }
  __syncthreads();
  for (int i = threadIdx.x; i < NCAND; i += 1024){
    u64 kw = ~sup[i >> 6];
    if ((kw >> (i & 63)) & 1ull){
      u32 rank = pref[i >> 6] + (u32)__popcll(kw & ((1ull << (i & 63)) - 1ull));
      if (rank < POSTN){
        const float* bp = sbox + ((size_t)(b*NCAND + i))*5;
        float* op = out + ((size_t)(b*POSTN + rank))*5;
        op[0]=bp[0]; op[1]=bp[1]; op[2]=bp[2]; op[3]=bp[3]; op[4]=bp[4];
        out[(size_t)NB*POSTN*5 + b*POSTN + rank] = sscore[b*NCAND + i];
      }
    }
  }
}

// ---------------------------------------------------------------------------
extern "C" void kernel_launch(void* const* d_in, const int* in_sizes, int n_in,
                              void* d_out, int out_size, void* d_ws, size_t ws_size,
                              hipStream_t stream)
{
  (void)out_size; (void)ws_size;
  const float *obj[4] = {nullptr,nullptr,nullptr,nullptr};
  const float *dlt[4] = {nullptr,nullptr,nullptr,nullptr};
  const float *anchors = nullptr;
  for (int i = 0; i < n_in; ++i){
    int s = in_sizes[i];
    const float* p = (const float*)d_in[i];
    switch (s){
      case 786432:  obj[0] = p; break;
      case 4718592: dlt[0] = p; break;
      case 196608:  obj[1] = p; break;
      case 1179648: dlt[1] = p; break;
      case 49152:   obj[2] = p; break;
      case 294912:  dlt[2] = p; break;
      case 12288:   obj[3] = p; break;
      case 73728:   dlt[3] = p; break;
      case 5222400: anchors = p; break;
      default: break;
    }
  }

  char* wsb = (char*)d_ws;
  size_t off = 0;
  auto alloc = [&](size_t bytes)->void*{
    size_t cur = (off + 255) & ~(size_t)255;
    off = cur + bytes;
    return (void*)(wsb + cur);
  };
  int*   cand_j = (int*)  alloc(16*KSEL*sizeof(int));
  float* cscore = (float*)alloc((size_t)NB*NCAND*sizeof(float));
  u32*   csmono = (u32*)  alloc((size_t)NB*NCAND*sizeof(u32));
  u64*   ctb    = (u64*)  alloc((size_t)NB*NCAND*sizeof(u64));
  float* cbox   = (float*)alloc((size_t)NB*NCAND*5*sizeof(float));
  u8*    cvalid = (u8*)   alloc((size_t)NB*NCAND);
  float* sscore = (float*)alloc((size_t)NB*NCAND*sizeof(float));
  float* sbox   = (float*)alloc((size_t)NB*NCAND*5*sizeof(float));
  u8*    svalid = (u8*)   alloc((size_t)NB*NCAND);
  float* geom   = (float*)alloc((size_t)NB*NCAND*16*sizeof(float));
  u64*   maskp  = (u64*)  alloc((size_t)NB*NCAND*32*sizeof(u64));

  hipLaunchKernelGGL(k1_topk, dim3(16), dim3(1024), 0, stream,
                     obj[0], obj[1], obj[2], obj[3], cand_j);
  hipLaunchKernelGGL(k2_decode, dim3(32), dim3(256), 0, stream,
                     obj[0], obj[1], obj[2], obj[3],
                     dlt[0], dlt[1], dlt[2], dlt[3],
                     anchors, cand_j, cscore, csmono, ctb, cbox, cvalid);
  hipLaunchKernelGGL(k3_sort, dim3(4), dim3(1024), 0, stream,
                     csmono, ctb, cscore, cbox, cvalid, sscore, sbox, geom, svalid);
  hipLaunchKernelGGL(k4_mask, dim3(65536), dim3(256), 0, stream, geom, maskp);
  hipLaunchKernelGGL(k5_nms_out, dim3(4), dim3(1024), 0, stream,
                     maskp, svalid, sbox, sscore, (float*)d_out);
}

// Round 5
// 466.618 us; speedup vs baseline: 6.8099x; 1.0959x over previous
//
#include <hip/hip_runtime.h>

typedef unsigned int u32;
typedef unsigned long long u64;
typedef unsigned char u8;

#define NB 4
#define T_ANCH 261120
#define NCAND 2048          // candidates per image (4 levels x 512)
#define KSEL 512
#define POSTN 512
#define LOG_MAXF 4.135166556742356f
#define NMS_TH 0.7f
#define LVL_OFF_F 8192.0f
#define BINS 4096           // top-12 bits of mono32
#define EQCAP 8192          // tie-bin capacity (expected ~300-700 occupants)

__device__ __forceinline__ u32 mono32(float f){
  u32 u = __float_as_uint(f);
  return (u & 0x80000000u) ? ~u : (u | 0x80000000u);
}
__device__ __forceinline__ int lvl_hw(int lvl){ return 65536 >> (2*lvl); }
__device__ __forceinline__ int lvl_off(int lvl){
  return (lvl>0?196608:0) + (lvl>1?49152:0) + (lvl>2?12288:0);
}

// ---------------------------------------------------------------------------
// K1: exact top-512 per (image, level) by key (mono(obj)<<32 | ~j) where j is
// the PERMUTED index (j = pix*3 + a). See R4 notes.
// ---------------------------------------------------------------------------
__global__ __launch_bounds__(1024) void k1_topk(
    const float* __restrict__ o0, const float* __restrict__ o1,
    const float* __restrict__ o2, const float* __restrict__ o3,
    int* __restrict__ cand_j)
{
  int bid = blockIdx.x;
  int b = bid >> 2, lvl = bid & 3;
  const float* ob = (lvl==0)?o0 : (lvl==1)?o1 : (lvl==2)?o2 : o3;
  int hw = lvl_hw(lvl);
  int size = 3*hw;                       // 196608 / 49152 / 12288 / 3072
  const float* base = ob + (size_t)b*size;
  const float4* b4 = (const float4*)base;  // size % 4 == 0, 16B-aligned
  int n4 = size >> 2;

  __shared__ u32 hist[BINS];
  __shared__ u64 eqbuf[EQCAP];
  __shared__ u32 coarse[64];
  __shared__ u32 s_b0, s_cntAbove, s_eqn, s_emit;

  int t = threadIdx.x;

  for (int i = t; i < BINS; i += 1024) hist[i] = 0;
  if (t == 0){ s_eqn = 0; s_emit = 0; }
  __syncthreads();

  // ---- Pass A: histogram of top-12 bits (value-only; order-independent) ----
  for (int i = t; i < n4; i += 1024){
    float4 v = b4[i];
    atomicAdd(&hist[mono32(v.x) >> 20], 1u);
    atomicAdd(&hist[mono32(v.y) >> 20], 1u);
    atomicAdd(&hist[mono32(v.z) >> 20], 1u);
    atomicAdd(&hist[mono32(v.w) >> 20], 1u);
  }
  __syncthreads();

  // ---- Coarse sums, then serial two-level descending walk ----
  if (t < 64){
    u32 s = 0;
    for (int z = 0; z < 64; ++z) s += hist[t*64 + z];
    coarse[t] = s;
  }
  __syncthreads();
  if (t == 0){
    u32 acc = 0;
    int cb = 63;
    while (acc + coarse[cb] < (u32)KSEL){ acc += coarse[cb]; --cb; }
    int z = cb*64 + 63;
    while (acc + hist[z] < (u32)KSEL){ acc += hist[z]; --z; }
    s_b0 = (u32)z;          // bin containing the 512th-largest key
    s_cntAbove = acc;       // count of elements in bins > b0  (< 512)
  }
  __syncthreads();
  u32 b0v = s_b0, cA = s_cntAbove;

  // ---- Pass B: classify (emit PERMUTED index j = (pix+q)*3 + a) ----
  for (int i = t; i < n4; i += 1024){
    float4 v = b4[i];
    int L = i << 2;                 // linear base index (= a*hw + pix)
    int a = L / hw;                 // same for all 4 lanes (hw % 4 == 0)
    int pix = L - a*hw;
    int j0 = pix*3 + a;             // permuted index of element q is j0 + 3q
    u32 m0 = mono32(v.x), m1 = mono32(v.y), m2 = mono32(v.z), m3 = mono32(v.w);
    u32 bb0 = m0 >> 20, bb1 = m1 >> 20, bb2 = m2 >> 20, bb3 = m3 >> 20;
    if (bb0 > b0v){ u32 s = atomicAdd(&s_emit,1u); if (s < (u32)KSEL) cand_j[bid*KSEL+s] = j0; }
    else if (bb0 == b0v){ u32 s = atomicAdd(&s_eqn,1u); if (s < (u32)EQCAP) eqbuf[s] = ((u64)m0<<32) | (u32)(~(u32)j0); }
    if (bb1 > b0v){ u32 s = atomicAdd(&s_emit,1u); if (s < (u32)KSEL) cand_j[bid*KSEL+s] = j0+3; }
    else if (bb1 == b0v){ u32 s = atomicAdd(&s_eqn,1u); if (s < (u32)EQCAP) eqbuf[s] = ((u64)m1<<32) | (u32)(~(u32)(j0+3)); }
    if (bb2 > b0v){ u32 s = atomicAdd(&s_emit,1u); if (s < (u32)KSEL) cand_j[bid*KSEL+s] = j0+6; }
    else if (bb2 == b0v){ u32 s = atomicAdd(&s_eqn,1u); if (s < (u32)EQCAP) eqbuf[s] = ((u64)m2<<32) | (u32)(~(u32)(j0+6)); }
    if (bb3 > b0v){ u32 s = atomicAdd(&s_emit,1u); if (s < (u32)KSEL) cand_j[bid*KSEL+s] = j0+9; }
    else if (bb3 == b0v){ u32 s = atomicAdd(&s_eqn,1u); if (s < (u32)EQCAP) eqbuf[s] = ((u64)m3<<32) | (u32)(~(u32)(j0+9)); }
  }
  __syncthreads();

  // ---- Tie resolution: O(n^2) exact rank-select ----
  u32 n = s_eqn < (u32)EQCAP ? s_eqn : (u32)EQCAP;
  u32 k = (u32)KSEL - cA;                 // >= 1, <= 512
  for (u32 i = t; i < n; i += 1024){
    u64 ki = eqbuf[i];
    u32 r = 0;
    for (u32 mm = 0; mm < n; ++mm) r += (eqbuf[mm] > ki) ? 1u : 0u;
    if (r < k){
      u32 s = atomicAdd(&s_emit, 1u);
      if (s < (u32)KSEL) cand_j[bid*KSEL + s] = (int)(~(u32)ki);
    }
  }
}

// ---------------------------------------------------------------------------
// K2: decode the 8192 selected candidates; build sort keys.
// ---------------------------------------------------------------------------
__global__ __launch_bounds__(256) void k2_decode(
    const float* __restrict__ o0, const float* __restrict__ o1,
    const float* __restrict__ o2, const float* __restrict__ o3,
    const float* __restrict__ d0, const float* __restrict__ d1,
    const float* __restrict__ d2, const float* __restrict__ d3,
    const float* __restrict__ anchors,
    const int* __restrict__ cand_j,
    float* __restrict__ cscore, u32* __restrict__ csmono,
    u64* __restrict__ ctb, float* __restrict__ cbox, u8* __restrict__ cvalid)
{
  int c = blockIdx.x*256 + threadIdx.x;
  if (c >= NB*NCAND) return;
  int pair = c >> 9;          // (b,lvl) pair index
  int b = pair >> 2, lvl = pair & 3;
  int j = cand_j[c];
  int hw = lvl_hw(lvl);
  u32 pix = (u32)j / 3u;
  u32 a = (u32)j - pix*3u;
  const float* ob = (lvl==0)?o0 : (lvl==1)?o1 : (lvl==2)?o2 : o3;
  const float* dl = (lvl==0)?d0 : (lvl==1)?d1 : (lvl==2)?d2 : d3;

  float ov = ob[(size_t)(b*3 + (int)a)*hw + pix];
  size_t dbase = ((size_t)(b*3 + (int)a)*6)*(size_t)hw + pix;
  float dx  = dl[dbase + 0*(size_t)hw];
  float dy  = dl[dbase + 1*(size_t)hw];
  float dw  = dl[dbase + 2*(size_t)hw];
  float dh  = dl[dbase + 3*(size_t)hw];
  float dsn = dl[dbase + 4*(size_t)hw];
  float dcs = dl[dbase + 5*(size_t)hw];
  int tt = lvl_off(lvl) + j;
  const float* an = anchors + ((size_t)b*T_ANCH + tt)*5;
  float ax=an[0], ay=an[1], aw=an[2], ah=an[3], aa=an[4];
  dw = fminf(dw, LOG_MAXF); dh = fminf(dh, LOG_MAXF);
  float cx = ax + dx*aw;
  float cy = ay + dy*ah;
  float w  = aw * expf(dw);
  float h  = ah * expf(dh);
  float ang = aa + atan2f(dsn, dcs);
  double sd = 1.0 / (1.0 + exp(-(double)ov));
  float sc = (float)sd;
  bool valid = (w >= 1e-3f) && (h >= 1e-3f) && (sc >= 0.0f);
  cscore[c] = sc;
  csmono[c] = valid ? mono32(sc) : 0u;        // invalid => -inf (stable-sorted by tb)
  // tiebreak: level asc, obj desc, idx asc  (== reference positional order)
  ctb[c] = ((u64)lvl << 50) | ((u64)(u32)(~mono32(ov)) << 18) | (u64)(u32)j;
  cvalid[c] = valid ? 1 : 0;
  float* bb = cbox + (size_t)c*5;
  bb[0]=cx; bb[1]=cy; bb[2]=w; bb[3]=h; bb[4]=ang;
}

// ---------------------------------------------------------------------------
// K3: per-image stable-equivalent sort (score desc, tb asc) via bitonic in LDS,
// then gather sorted arrays + offset corners / AABB / area geometry.
// ---------------------------------------------------------------------------
__global__ __launch_bounds__(1024) void k3_sort(
    const u32* __restrict__ csmono, const u64* __restrict__ ctb,
    const float* __restrict__ cscore, const float* __restrict__ cbox,
    const u8* __restrict__ cvalid,
    float* __restrict__ sscore, float* __restrict__ sbox,
    float* __restrict__ geom, u8* __restrict__ svalid)
{
  int b = blockIdx.x;
  __shared__ u32 sm[NCAND];
  __shared__ u64 stb[NCAND];
  __shared__ u32 sid[NCAND];
  for (int k = threadIdx.x; k < NCAND; k += 1024){
    sm[k]  = csmono[b*NCAND + k];
    stb[k] = ctb[b*NCAND + k];
    sid[k] = (u32)k;
  }
  __syncthreads();
  for (int kk = 2; kk <= NCAND; kk <<= 1){
    for (int jj = kk >> 1; jj > 0; jj >>= 1){
      for (int i = threadIdx.x; i < NCAND; i += 1024){
        int ixj = i ^ jj;
        if (ixj > i){
          bool dirAsc = ((i & kk) == 0);
          u32 s1 = sm[i], s2 = sm[ixj];
          u64 t1 = stb[i], t2 = stb[ixj];
          bool before_ixj = (s2 > s1) || (s2 == s1 && t2 < t1);
          bool sw = dirAsc ? before_ixj : !before_ixj;
          if (sw){
            sm[i]=s2; sm[ixj]=s1;
            stb[i]=t2; stb[ixj]=t1;
            u32 tmp = sid[i]; sid[i]=sid[ixj]; sid[ixj]=tmp;
          }
        }
      }
      __syncthreads();
    }
  }
  for (int k = threadIdx.x; k < NCAND; k += 1024){
    int id = (int)sid[k];
    int gsrc = b*NCAND + id;
    int gdst = b*NCAND + k;
    float scv = cscore[gsrc];
    sscore[gdst] = scv;
    svalid[gdst] = cvalid[gsrc];
    float b0 = cbox[(size_t)gsrc*5+0], b1 = cbox[(size_t)gsrc*5+1];
    float b2 = cbox[(size_t)gsrc*5+2], b3 = cbox[(size_t)gsrc*5+3];
    float b4 = cbox[(size_t)gsrc*5+4];
    float* sb = sbox + (size_t)gdst*5;
    sb[0]=b0; sb[1]=b1; sb[2]=b2; sb[3]=b3; sb[4]=b4;
    int lvl = (int)((stb[k] >> 50) & 3ull);
    float offv = (float)lvl * LVL_OFF_F;
    float cx = b0 + offv, cy = b1 + offv, w=b2, h=b3, ang=b4;
    float cc = cosf(ang), sn = sinf(ang);
    float hx = 0.5f*w, hy = 0.5f*h;
    float x0 = cx + hx*cc - hy*sn, y0 = cy + hx*sn + hy*cc;
    float x1 = cx - hx*cc - hy*sn, y1 = cy - hx*sn + hy*cc;
    float x2 = cx - hx*cc + hy*sn, y2 = cy - hx*sn - hy*cc;
    float x3 = cx + hx*cc + hy*sn, y3 = cy + hx*sn - hy*cc;
    float minx = fminf(fminf(x0,x1),fminf(x2,x3));
    float maxx = fmaxf(fmaxf(x0,x1),fmaxf(x2,x3));
    float miny = fminf(fminf(y0,y1),fminf(y2,y3));
    float maxy = fmaxf(fmaxf(y0,y1),fmaxf(y2,y3));
    float* g = geom + (size_t)gdst*16;
    g[0]=minx; g[1]=maxx; g[2]=miny; g[3]=maxy; g[4]=w*h;
    g[5]=x0; g[6]=y0; g[7]=x1; g[8]=y1; g[9]=x2; g[10]=y2; g[11]=x3; g[12]=y3;
  }
}

// ---------------------------------------------------------------------------
// K4: rotated-IoU suppression mask. One lane per (i,j) pair, ballot -> word.
// ---------------------------------------------------------------------------
__device__ __forceinline__ void emit_pt(float* ox, float* oy, int oc, float x, float y){
  #pragma unroll
  for (int s = 0; s < 8; ++s) if (s == oc){ ox[s] = x; oy[s] = y; }
}

__device__ float quad_inter(const float* ca, const float* cb){
  float px[8], py[8];
  #pragma unroll
  for (int q = 0; q < 8; ++q){ px[q]=0.f; py[q]=0.f; }
  #pragma unroll
  for (int q = 0; q < 4; ++q){ px[q]=ca[2*q]; py[q]=ca[2*q+1]; }
  int cnt = 4;
  #pragma unroll
  for (int e = 0; e < 4; ++e){
    float p1x = cb[2*e],         p1y = cb[2*e+1];
    float p2x = cb[(2*e+2)&7],   p2y = cb[(2*e+3)&7];
    float ex = p2x-p1x, ey = p2y-p1y;
    float d[8];
    #pragma unroll
    for (int q = 0; q < 8; ++q) d[q] = ex*(py[q]-p1y) - ey*(px[q]-p1x);
    float ox[8], oy[8];
    #pragma unroll
    for (int q = 0; q < 8; ++q){ ox[q]=0.f; oy[q]=0.f; }
    int oc = 0;
    #pragma unroll
    for (int q = 0; q < 8; ++q){
      if (q < cnt){
        bool last = (q+1 >= cnt);
        float dn  = last ? d[0]  : d[(q+1)&7];
        bool in0 = (d[q] >= 0.0f), in1 = (dn >= 0.0f);
        if (in0){ emit_pt(ox,oy,oc,px[q],py[q]); oc++; }
        if (in0 != in1){
          float pnx = last ? px[0] : px[(q+1)&7];
          float pny = last ? py[0] : py[(q+1)&7];
          float den = d[q] - dn;
          float t = d[q] / ((den == 0.0f) ? 1.0f : den);
          emit_pt(ox,oy,oc, px[q] + t*(pnx-px[q]), py[q] + t*(pny-py[q]));
          oc++;
        }
      }
    }
    cnt = (oc > 8) ? 8 : oc;
    #pragma unroll
    for (int q = 0; q < 8; ++q){ px[q]=ox[q]; py[q]=oy[q]; }
  }
  if (cnt < 3) return 0.0f;
  float s = 0.0f;
  #pragma unroll
  for (int q = 0; q < 8; ++q){
    if (q < cnt){
      bool last = (q+1 >= cnt);
      float pnx = last ? px[0] : px[(q+1)&7];
      float pny = last ? py[0] : py[(q+1)&7];
      s += px[q]*pny - pnx*py[q];
    }
  }
  return 0.5f*fabsf(s);
}

__global__ __launch_bounds__(256) void k4_mask(
    const float* __restrict__ geom, u64* __restrict__ mask)
{
  int gt = blockIdx.x*256 + threadIdx.x;
  int img = gt >> 22;
  int rem = gt & ((1<<22)-1);
  int i = rem >> 11;
  int j = rem & (NCAND-1);
  bool bit = false;
  if (j > i){
    const float* gi = geom + ((size_t)(img*NCAND + i))*16;
    const float* gj = geom + ((size_t)(img*NCAND + j))*16;
    // AABB quick reject (decision-safe: disjoint => iou == 0)
    if (!(gi[0] > gj[1] || gj[0] > gi[1] || gi[2] > gj[3] || gj[2] > gi[3])){
      float inter = quad_inter(gi+5, gj+5);
      float iou = inter / (gi[4] + gj[4] - inter + 1e-7f);
      bit = (iou > NMS_TH);
    }
  }
  u64 bm = __ballot(bit);
  if ((threadIdx.x & 63) == 0)
    mask[((size_t)(img*NCAND + i))*32 + (j >> 6)] = bm;
}

// ---------------------------------------------------------------------------
// K5: sequential greedy suppression with the sup vector in WAVE-0 REGISTERS
// (lane l holds sup word l as two u32 halves; per-row current word fetched
// via v_readlane with a wave-uniform index — no LDS on the serial chain).
// Mask chunks double-buffered in LDS: waves 1..15 load chunk c+1 while wave 0
// walks chunk c. Then ranked output of first 512 kept.
// ---------------------------------------------------------------------------
__global__ __launch_bounds__(1024) void k5_nms_out(
    const u64* __restrict__ mask, const u8* __restrict__ svalid,
    const float* __restrict__ sbox, const float* __restrict__ sscore,
    float* __restrict__ out)
{
  int b = blockIdx.x;
  __shared__ u64 buf[2][128*32];      // 64 KB double buffer
  __shared__ u64 s_sup[32];
  __shared__ u32 pref[32];
  int t = threadIdx.x;
  int wid = t >> 6, lane = t & 63;

  // sup init from svalid: lane l (l<32) builds word l; lanes 32-63 mirror
  // lanes 0-31 (their result is unused) to keep the wave convergent.
  u32 slo = 0, shi = 0;
  if (wid == 0){
    int wl = lane & 31;
    u64 w = 0;
    for (int q = 0; q < 64; ++q)
      if (!svalid[b*NCAND + wl*64 + q]) w |= (1ull << q);
    slo = (u32)w; shi = (u32)(w >> 32);
  }
  // preload chunk 0 (all waves)
  {
    const u64* src = mask + ((size_t)b*NCAND)*32;
    for (int x = t; x < 128*32; x += 1024) buf[0][x] = src[x];
  }
  __syncthreads();

  for (int c = 0; c < 16; ++c){
    if (wid != 0){
      if (c + 1 < 16){
        const u64* src = mask + ((size_t)(b*NCAND + (c+1)*128))*32;
        for (int x = t - 64; x < 128*32; x += (1024 - 64))
          buf[(c+1)&1][x] = src[x];
      }
    } else {
      const u64* ch = buf[c&1];
      #pragma unroll 4
      for (int r = 0; r < 128; ++r){
        int gi = c*128 + r;
        int wi = gi >> 6;                       // wave-uniform
        u64 v = ch[r*32 + (lane & 31)];         // unconditional: pipelines ahead
        u32 wlo = (u32)__builtin_amdgcn_readlane((int)slo, wi);
        u32 whi = (u32)__builtin_amdgcn_readlane((int)shi, wi);
        u64 w = ((u64)whi << 32) | wlo;
        bool keep = !((w >> (gi & 63)) & 1ull);
        if (keep){ slo |= (u32)v; shi |= (u32)(v >> 32); }
      }
    }
    __syncthreads();
  }
  if (wid == 0 && lane < 32) s_sup[lane] = ((u64)shi << 32) | slo;
  __syncthreads();

  // zero-fill this image's output (d_out is poisoned before every launch)
  for (int x = t; x < POSTN*5; x += 1024) out[(size_t)b*POSTN*5 + x] = 0.0f;
  for (int x = t; x < POSTN;   x += 1024) out[(size_t)NB*POSTN*5 + b*POSTN + x] = 0.0f;
  if (t < 32) pref[t] = (u32)__popcll(~s_sup[t]);
  __syncthreads();
  if (t == 0){
    u32 run = 0;
    for (int w = 0; w < 32; ++w){ u32 tv = pref[w]; pref[w] = run; run += tv; }
  }
  __syncthreads();
  for (int i = t; i < NCAND; i += 1024){
    u64 kw = ~s_sup[i >> 6];
    if ((kw >> (i & 63)) & 1ull){
      u32 rank = pref[i >> 6] + (u32)__popcll(kw & ((1ull << (i & 63)) - 1ull));
      if (rank < POSTN){
        const float* bp = sbox + ((size_t)(b*NCAND + i))*5;
        float* op = out + ((size_t)(b*POSTN + rank))*5;
        op[0]=bp[0]; op[1]=bp[1]; op[2]=bp[2]; op[3]=bp[3]; op[4]=bp[4];
        out[(size_t)NB*POSTN*5 + b*POSTN + rank] = sscore[b*NCAND + i];
      }
    }
  }
}

// ---------------------------------------------------------------------------
extern "C" void kernel_launch(void* const* d_in, const int* in_sizes, int n_in,
                              void* d_out, int out_size, void* d_ws, size_t ws_size,
                              hipStream_t stream)
{
  (void)out_size; (void)ws_size;
  const float *obj[4] = {nullptr,nullptr,nullptr,nullptr};
  const float *dlt[4] = {nullptr,nullptr,nullptr,nullptr};
  const float *anchors = nullptr;
  for (int i = 0; i < n_in; ++i){
    int s = in_sizes[i];
    const float* p = (const float*)d_in[i];
    switch (s){
      case 786432:  obj[0] = p; break;
      case 4718592: dlt[0] = p; break;
      case 196608:  obj[1] = p; break;
      case 1179648: dlt[1] = p; break;
      case 49152:   obj[2] = p; break;
      case 294912:  dlt[2] = p; break;
      case 12288:   obj[3] = p; break;
      case 73728:   dlt[3] = p; break;
      case 5222400: anchors = p; break;
      default: break;
    }
  }

  char* wsb = (char*)d_ws;
  size_t off = 0;
  auto alloc = [&](size_t bytes)->void*{
    size_t cur = (off + 255) & ~(size_t)255;
    off = cur + bytes;
    return (void*)(wsb + cur);
  };
  int*   cand_j = (int*)  alloc(16*KSEL*sizeof(int));
  float* cscore = (float*)alloc((size_t)NB*NCAND*sizeof(float));
  u32*   csmono = (u32*)  alloc((size_t)NB*NCAND*sizeof(u32));
  u64*   ctb    = (u64*)  alloc((size_t)NB*NCAND*sizeof(u64));
  float* cbox   = (float*)alloc((size_t)NB*NCAND*5*sizeof(float));
  u8*    cvalid = (u8*)   alloc((size_t)NB*NCAND);
  float* sscore = (float*)alloc((size_t)NB*NCAND*sizeof(float));
  float* sbox   = (float*)alloc((size_t)NB*NCAND*5*sizeof(float));
  u8*    svalid = (u8*)   alloc((size_t)NB*NCAND);
  float* geom   = (float*)alloc((size_t)NB*NCAND*16*sizeof(float));
  u64*   maskp  = (u64*)  alloc((size_t)NB*NCAND*32*sizeof(u64));

  hipLaunchKernelGGL(k1_topk, dim3(16), dim3(1024), 0, stream,
                     obj[0], obj[1], obj[2], obj[3], cand_j);
  hipLaunchKernelGGL(k2_decode, dim3(32), dim3(256), 0, stream,
                     obj[0], obj[1], obj[2], obj[3],
                     dlt[0], dlt[1], dlt[2], dlt[3],
                     anchors, cand_j, cscore, csmono, ctb, cbox, cvalid);
  hipLaunchKernelGGL(k3_sort, dim3(4), dim3(1024), 0, stream,
                     csmono, ctb, cscore, cbox, cvalid, sscore, sbox, geom, svalid);
  hipLaunchKernelGGL(k4_mask, dim3(65536), dim3(256), 0, stream, geom, maskp);
  hipLaunchKernelGGL(k5_nms_out, dim3(4), dim3(1024), 0, stream,
                     maskp, svalid, sbox, sscore, (float*)d_out);
}

// Round 6
// 359.537 us; speedup vs baseline: 8.8380x; 1.2978x over previous
//
#include <hip/hip_runtime.h>

typedef unsigned int u32;
typedef unsigned long long u64;
typedef unsigned char u8;

#define NB 4
#define T_ANCH 261120
#define NCAND 2048          // candidates per image (4 levels x 512)
#define KSEL 512
#define POSTN 512
#define LOG_MAXF 4.135166556742356f
#define NMS_TH 0.7f
#define LVL_OFF_F 8192.0f
#define BINS 4096           // top-12 bits of mono32
#define EQCAP 8192          // tie-bin capacity (expected ~300-700 occupants)

__device__ __forceinline__ u32 mono32(float f){
  u32 u = __float_as_uint(f);
  return (u & 0x80000000u) ? ~u : (u | 0x80000000u);
}
__device__ __forceinline__ int lvl_hw(int lvl){ return 65536 >> (2*lvl); }
__device__ __forceinline__ int lvl_off(int lvl){
  return (lvl>0?196608:0) + (lvl>1?49152:0) + (lvl>2?12288:0);
}

// ---------------------------------------------------------------------------
// K1: exact top-512 per (image, level) by key (mono(obj)<<32 | ~j) where j is
// the PERMUTED index (j = pix*3 + a). See R4 notes.
// ---------------------------------------------------------------------------
__global__ __launch_bounds__(1024) void k1_topk(
    const float* __restrict__ o0, const float* __restrict__ o1,
    const float* __restrict__ o2, const float* __restrict__ o3,
    int* __restrict__ cand_j)
{
  int bid = blockIdx.x;
  int b = bid >> 2, lvl = bid & 3;
  const float* ob = (lvl==0)?o0 : (lvl==1)?o1 : (lvl==2)?o2 : o3;
  int hw = lvl_hw(lvl);
  int size = 3*hw;                       // 196608 / 49152 / 12288 / 3072
  const float* base = ob + (size_t)b*size;
  const float4* b4 = (const float4*)base;  // size % 4 == 0, 16B-aligned
  int n4 = size >> 2;

  __shared__ u32 hist[BINS];
  __shared__ u64 eqbuf[EQCAP];
  __shared__ u32 coarse[64];
  __shared__ u32 s_b0, s_cntAbove, s_eqn, s_emit;

  int t = threadIdx.x;

  for (int i = t; i < BINS; i += 1024) hist[i] = 0;
  if (t == 0){ s_eqn = 0; s_emit = 0; }
  __syncthreads();

  // ---- Pass A: histogram of top-12 bits (value-only; order-independent) ----
  for (int i = t; i < n4; i += 1024){
    float4 v = b4[i];
    atomicAdd(&hist[mono32(v.x) >> 20], 1u);
    atomicAdd(&hist[mono32(v.y) >> 20], 1u);
    atomicAdd(&hist[mono32(v.z) >> 20], 1u);
    atomicAdd(&hist[mono32(v.w) >> 20], 1u);
  }
  __syncthreads();

  // ---- Coarse sums, then serial two-level descending walk ----
  if (t < 64){
    u32 s = 0;
    for (int z = 0; z < 64; ++z) s += hist[t*64 + z];
    coarse[t] = s;
  }
  __syncthreads();
  if (t == 0){
    u32 acc = 0;
    int cb = 63;
    while (acc + coarse[cb] < (u32)KSEL){ acc += coarse[cb]; --cb; }
    int z = cb*64 + 63;
    while (acc + hist[z] < (u32)KSEL){ acc += hist[z]; --z; }
    s_b0 = (u32)z;          // bin containing the 512th-largest key
    s_cntAbove = acc;       // count of elements in bins > b0  (< 512)
  }
  __syncthreads();
  u32 b0v = s_b0, cA = s_cntAbove;

  // ---- Pass B: classify (emit PERMUTED index j = (pix+q)*3 + a) ----
  for (int i = t; i < n4; i += 1024){
    float4 v = b4[i];
    int L = i << 2;                 // linear base index (= a*hw + pix)
    int a = L / hw;                 // same for all 4 lanes (hw % 4 == 0)
    int pix = L - a*hw;
    int j0 = pix*3 + a;             // permuted index of element q is j0 + 3q
    u32 m0 = mono32(v.x), m1 = mono32(v.y), m2 = mono32(v.z), m3 = mono32(v.w);
    u32 bb0 = m0 >> 20, bb1 = m1 >> 20, bb2 = m2 >> 20, bb3 = m3 >> 20;
    if (bb0 > b0v){ u32 s = atomicAdd(&s_emit,1u); if (s < (u32)KSEL) cand_j[bid*KSEL+s] = j0; }
    else if (bb0 == b0v){ u32 s = atomicAdd(&s_eqn,1u); if (s < (u32)EQCAP) eqbuf[s] = ((u64)m0<<32) | (u32)(~(u32)j0); }
    if (bb1 > b0v){ u32 s = atomicAdd(&s_emit,1u); if (s < (u32)KSEL) cand_j[bid*KSEL+s] = j0+3; }
    else if (bb1 == b0v){ u32 s = atomicAdd(&s_eqn,1u); if (s < (u32)EQCAP) eqbuf[s] = ((u64)m1<<32) | (u32)(~(u32)(j0+3)); }
    if (bb2 > b0v){ u32 s = atomicAdd(&s_emit,1u); if (s < (u32)KSEL) cand_j[bid*KSEL+s] = j0+6; }
    else if (bb2 == b0v){ u32 s = atomicAdd(&s_eqn,1u); if (s < (u32)EQCAP) eqbuf[s] = ((u64)m2<<32) | (u32)(~(u32)(j0+6)); }
    if (bb3 > b0v){ u32 s = atomicAdd(&s_emit,1u); if (s < (u32)KSEL) cand_j[bid*KSEL+s] = j0+9; }
    else if (bb3 == b0v){ u32 s = atomicAdd(&s_eqn,1u); if (s < (u32)EQCAP) eqbuf[s] = ((u64)m3<<32) | (u32)(~(u32)(j0+9)); }
  }
  __syncthreads();

  // ---- Tie resolution: O(n^2) exact rank-select ----
  u32 n = s_eqn < (u32)EQCAP ? s_eqn : (u32)EQCAP;
  u32 k = (u32)KSEL - cA;                 // >= 1, <= 512
  for (u32 i = t; i < n; i += 1024){
    u64 ki = eqbuf[i];
    u32 r = 0;
    for (u32 mm = 0; mm < n; ++mm) r += (eqbuf[mm] > ki) ? 1u : 0u;
    if (r < k){
      u32 s = atomicAdd(&s_emit, 1u);
      if (s < (u32)KSEL) cand_j[bid*KSEL + s] = (int)(~(u32)ki);
    }
  }
}

// ---------------------------------------------------------------------------
// K2: decode the 8192 selected candidates; build sort keys.
// ---------------------------------------------------------------------------
__global__ __launch_bounds__(256) void k2_decode(
    const float* __restrict__ o0, const float* __restrict__ o1,
    const float* __restrict__ o2, const float* __restrict__ o3,
    const float* __restrict__ d0, const float* __restrict__ d1,
    const float* __restrict__ d2, const float* __restrict__ d3,
    const float* __restrict__ anchors,
    const int* __restrict__ cand_j,
    float* __restrict__ cscore, u32* __restrict__ csmono,
    u64* __restrict__ ctb, float* __restrict__ cbox, u8* __restrict__ cvalid)
{
  int c = blockIdx.x*256 + threadIdx.x;
  if (c >= NB*NCAND) return;
  int pair = c >> 9;          // (b,lvl) pair index
  int b = pair >> 2, lvl = pair & 3;
  int j = cand_j[c];
  int hw = lvl_hw(lvl);
  u32 pix = (u32)j / 3u;
  u32 a = (u32)j - pix*3u;
  const float* ob = (lvl==0)?o0 : (lvl==1)?o1 : (lvl==2)?o2 : o3;
  const float* dl = (lvl==0)?d0 : (lvl==1)?d1 : (lvl==2)?d2 : d3;

  float ov = ob[(size_t)(b*3 + (int)a)*hw + pix];
  size_t dbase = ((size_t)(b*3 + (int)a)*6)*(size_t)hw + pix;
  float dx  = dl[dbase + 0*(size_t)hw];
  float dy  = dl[dbase + 1*(size_t)hw];
  float dw  = dl[dbase + 2*(size_t)hw];
  float dh  = dl[dbase + 3*(size_t)hw];
  float dsn = dl[dbase + 4*(size_t)hw];
  float dcs = dl[dbase + 5*(size_t)hw];
  int tt = lvl_off(lvl) + j;
  const float* an = anchors + ((size_t)b*T_ANCH + tt)*5;
  float ax=an[0], ay=an[1], aw=an[2], ah=an[3], aa=an[4];
  dw = fminf(dw, LOG_MAXF); dh = fminf(dh, LOG_MAXF);
  float cx = ax + dx*aw;
  float cy = ay + dy*ah;
  float w  = aw * expf(dw);
  float h  = ah * expf(dh);
  float ang = aa + atan2f(dsn, dcs);
  double sd = 1.0 / (1.0 + exp(-(double)ov));
  float sc = (float)sd;
  bool valid = (w >= 1e-3f) && (h >= 1e-3f) && (sc >= 0.0f);
  cscore[c] = sc;
  csmono[c] = valid ? mono32(sc) : 0u;        // invalid => -inf (stable-sorted by tb)
  // tiebreak: level asc, obj desc, idx asc  (== reference positional order)
  ctb[c] = ((u64)lvl << 50) | ((u64)(u32)(~mono32(ov)) << 18) | (u64)(u32)j;
  cvalid[c] = valid ? 1 : 0;
  float* bb = cbox + (size_t)c*5;
  bb[0]=cx; bb[1]=cy; bb[2]=w; bb[3]=h; bb[4]=ang;
}

// ---------------------------------------------------------------------------
// K3: per-image stable-equivalent sort (score desc, tb asc) via bitonic in LDS,
// then gather sorted arrays + offset corners / AABB / area geometry.
// ---------------------------------------------------------------------------
__global__ __launch_bounds__(1024) void k3_sort(
    const u32* __restrict__ csmono, const u64* __restrict__ ctb,
    const float* __restrict__ cscore, const float* __restrict__ cbox,
    const u8* __restrict__ cvalid,
    float* __restrict__ sscore, float* __restrict__ sbox,
    float* __restrict__ geom, u8* __restrict__ svalid)
{
  int b = blockIdx.x;
  __shared__ u32 sm[NCAND];
  __shared__ u64 stb[NCAND];
  __shared__ u32 sid[NCAND];
  for (int k = threadIdx.x; k < NCAND; k += 1024){
    sm[k]  = csmono[b*NCAND + k];
    stb[k] = ctb[b*NCAND + k];
    sid[k] = (u32)k;
  }
  __syncthreads();
  for (int kk = 2; kk <= NCAND; kk <<= 1){
    for (int jj = kk >> 1; jj > 0; jj >>= 1){
      for (int i = threadIdx.x; i < NCAND; i += 1024){
        int ixj = i ^ jj;
        if (ixj > i){
          bool dirAsc = ((i & kk) == 0);
          u32 s1 = sm[i], s2 = sm[ixj];
          u64 t1 = stb[i], t2 = stb[ixj];
          bool before_ixj = (s2 > s1) || (s2 == s1 && t2 < t1);
          bool sw = dirAsc ? before_ixj : !before_ixj;
          if (sw){
            sm[i]=s2; sm[ixj]=s1;
            stb[i]=t2; stb[ixj]=t1;
            u32 tmp = sid[i]; sid[i]=sid[ixj]; sid[ixj]=tmp;
          }
        }
      }
      __syncthreads();
    }
  }
  for (int k = threadIdx.x; k < NCAND; k += 1024){
    int id = (int)sid[k];
    int gsrc = b*NCAND + id;
    int gdst = b*NCAND + k;
    float scv = cscore[gsrc];
    sscore[gdst] = scv;
    svalid[gdst] = cvalid[gsrc];
    float b0 = cbox[(size_t)gsrc*5+0], b1 = cbox[(size_t)gsrc*5+1];
    float b2 = cbox[(size_t)gsrc*5+2], b3 = cbox[(size_t)gsrc*5+3];
    float b4 = cbox[(size_t)gsrc*5+4];
    float* sb = sbox + (size_t)gdst*5;
    sb[0]=b0; sb[1]=b1; sb[2]=b2; sb[3]=b3; sb[4]=b4;
    int lvl = (int)((stb[k] >> 50) & 3ull);
    float offv = (float)lvl * LVL_OFF_F;
    float cx = b0 + offv, cy = b1 + offv, w=b2, h=b3, ang=b4;
    float cc = cosf(ang), sn = sinf(ang);
    float hx = 0.5f*w, hy = 0.5f*h;
    float x0 = cx + hx*cc - hy*sn, y0 = cy + hx*sn + hy*cc;
    float x1 = cx - hx*cc - hy*sn, y1 = cy - hx*sn + hy*cc;
    float x2 = cx - hx*cc + hy*sn, y2 = cy - hx*sn - hy*cc;
    float x3 = cx + hx*cc + hy*sn, y3 = cy + hx*sn - hy*cc;
    float minx = fminf(fminf(x0,x1),fminf(x2,x3));
    float maxx = fmaxf(fmaxf(x0,x1),fmaxf(x2,x3));
    float miny = fminf(fminf(y0,y1),fminf(y2,y3));
    float maxy = fmaxf(fmaxf(y0,y1),fmaxf(y2,y3));
    float* g = geom + (size_t)gdst*16;
    g[0]=minx; g[1]=maxx; g[2]=miny; g[3]=maxy; g[4]=w*h;
    g[5]=x0; g[6]=y0; g[7]=x1; g[8]=y1; g[9]=x2; g[10]=y2; g[11]=x3; g[12]=y3;
  }
}

// ---------------------------------------------------------------------------
// K4: rotated-IoU suppression mask. One lane per (i,j) pair, ballot -> word.
// ---------------------------------------------------------------------------
__device__ __forceinline__ void emit_pt(float* ox, float* oy, int oc, float x, float y){
  #pragma unroll
  for (int s = 0; s < 8; ++s) if (s == oc){ ox[s] = x; oy[s] = y; }
}

__device__ float quad_inter(const float* ca, const float* cb){
  float px[8], py[8];
  #pragma unroll
  for (int q = 0; q < 8; ++q){ px[q]=0.f; py[q]=0.f; }
  #pragma unroll
  for (int q = 0; q < 4; ++q){ px[q]=ca[2*q]; py[q]=ca[2*q+1]; }
  int cnt = 4;
  #pragma unroll
  for (int e = 0; e < 4; ++e){
    float p1x = cb[2*e],         p1y = cb[2*e+1];
    float p2x = cb[(2*e+2)&7],   p2y = cb[(2*e+3)&7];
    float ex = p2x-p1x, ey = p2y-p1y;
    float d[8];
    #pragma unroll
    for (int q = 0; q < 8; ++q) d[q] = ex*(py[q]-p1y) - ey*(px[q]-p1x);
    float ox[8], oy[8];
    #pragma unroll
    for (int q = 0; q < 8; ++q){ ox[q]=0.f; oy[q]=0.f; }
    int oc = 0;
    #pragma unroll
    for (int q = 0; q < 8; ++q){
      if (q < cnt){
        bool last = (q+1 >= cnt);
        float dn  = last ? d[0]  : d[(q+1)&7];
        bool in0 = (d[q] >= 0.0f), in1 = (dn >= 0.0f);
        if (in0){ emit_pt(ox,oy,oc,px[q],py[q]); oc++; }
        if (in0 != in1){
          float pnx = last ? px[0] : px[(q+1)&7];
          float pny = last ? py[0] : py[(q+1)&7];
          float den = d[q] - dn;
          float t = d[q] / ((den == 0.0f) ? 1.0f : den);
          emit_pt(ox,oy,oc, px[q] + t*(pnx-px[q]), py[q] + t*(pny-py[q]));
          oc++;
        }
      }
    }
    cnt = (oc > 8) ? 8 : oc;
    #pragma unroll
    for (int q = 0; q < 8; ++q){ px[q]=ox[q]; py[q]=oy[q]; }
  }
  if (cnt < 3) return 0.0f;
  float s = 0.0f;
  #pragma unroll
  for (int q = 0; q < 8; ++q){
    if (q < cnt){
      bool last = (q+1 >= cnt);
      float pnx = last ? px[0] : px[(q+1)&7];
      float pny = last ? py[0] : py[(q+1)&7];
      s += px[q]*pny - pnx*py[q];
    }
  }
  return 0.5f*fabsf(s);
}

__global__ __launch_bounds__(256) void k4_mask(
    const float* __restrict__ geom, u64* __restrict__ mask)
{
  int gt = blockIdx.x*256 + threadIdx.x;
  int img = gt >> 22;
  int rem = gt & ((1<<22)-1);
  int i = rem >> 11;
  int j = rem & (NCAND-1);
  bool bit = false;
  if (j > i){
    const float* gi = geom + ((size_t)(img*NCAND + i))*16;
    const float* gj = geom + ((size_t)(img*NCAND + j))*16;
    // AABB quick reject (decision-safe: disjoint => iou == 0)
    if (!(gi[0] > gj[1] || gj[0] > gi[1] || gi[2] > gj[3] || gj[2] > gi[3])){
      float inter = quad_inter(gi+5, gj+5);
      float iou = inter / (gi[4] + gj[4] - inter + 1e-7f);
      bit = (iou > NMS_TH);
    }
  }
  u64 bm = __ballot(bit);
  if ((threadIdx.x & 63) == 0)
    mask[((size_t)(img*NCAND + i))*32 + (j >> 6)] = bm;
}

// ---------------------------------------------------------------------------
// K5: sequential greedy suppression, sup in wave-0 registers, with:
//  - EARLY EXIT at the 512th kept row (decision-safe: output = first 512 kept
//    rows in sorted order; later rows can't affect earlier decisions). Rows
//    after the stop row R are excluded via a range mask in the epilogue.
//  - branchless chain: 8 rows' ds_read batched into registers (independent of
//    sup), then 8 readlane+mask+or steps; only a scalar not-taken branch per
//    row for the exit check.
// Mask chunks (128 rows) double-buffered: waves 1..15 stage chunk c+1 while
// wave 0 walks chunk c; shared flag broadcasts the early exit.
// ---------------------------------------------------------------------------
__global__ __launch_bounds__(1024) void k5_nms_out(
    const u64* __restrict__ mask, const u8* __restrict__ svalid,
    const float* __restrict__ sbox, const float* __restrict__ sscore,
    float* __restrict__ out)
{
  int b = blockIdx.x;
  __shared__ u64 buf[2][128*32];      // 64 KB double buffer
  __shared__ u64 s_kept[32];
  __shared__ u32 pref[32];
  __shared__ u32 s_done, s_R;
  int t = threadIdx.x;
  int wid = t >> 6, lane = t & 63;

  if (t == 0){ s_done = 0; s_R = NCAND - 1; }

  // sup init from svalid: lane l (l<32) builds word l; lanes 32-63 mirror.
  u32 slo = 0, shi = 0;
  if (wid == 0){
    int wl = lane & 31;
    u64 w = 0;
    for (int q = 0; q < 64; ++q)
      if (!svalid[b*NCAND + wl*64 + q]) w |= (1ull << q);
    slo = (u32)w; shi = (u32)(w >> 32);
  }
  // preload chunk 0 (all waves)
  {
    const u64* src = mask + ((size_t)b*NCAND)*32;
    for (int x = t; x < 128*32; x += 1024) buf[0][x] = src[x];
  }
  __syncthreads();

  u32 kcnt = 0;
  bool stopped = false;
  for (int c = 0; c < 16; ++c){
    if (wid != 0){
      if (c + 1 < 16){
        const u64* src = mask + ((size_t)(b*NCAND + (c+1)*128))*32;
        for (int x = t - 64; x < 128*32; x += (1024 - 64))
          buf[(c+1)&1][x] = src[x];
      }
    } else if (!stopped){
      const u64* ch = buf[c&1];
      for (int r8 = 0; r8 < 128 && !stopped; r8 += 8){
        u64 v[8];
        #pragma unroll
        for (int q = 0; q < 8; ++q) v[q] = ch[(r8+q)*32 + (lane & 31)];
        #pragma unroll
        for (int q = 0; q < 8; ++q){
          int gi = c*128 + r8 + q;
          int wi = gi >> 6;                       // wave-uniform
          u32 wlo = (u32)__builtin_amdgcn_readlane((int)slo, wi);
          u32 whi = (u32)__builtin_amdgcn_readlane((int)shi, wi);
          u64 w = ((u64)whi << 32) | wlo;
          u32 keep = (u32)((~w >> (gi & 63)) & 1ull);
          u64 vm = v[q] & (0ull - (u64)keep);     // branchless: keep ? v : 0
          slo |= (u32)vm; shi |= (u32)(vm >> 32);
          kcnt += keep;
          if (kcnt >= (u32)POSTN){                // 512th keep -> stop
            if (lane == 0){ s_done = 1; s_R = (u32)gi; }
            stopped = true;
            break;
          }
        }
      }
    }
    __syncthreads();
    if (s_done) break;
    __syncthreads();
  }
  // publish kept words, range-masked to rows <= R
  if (wid == 0 && lane < 32){
    u32 Rv = s_R;
    int lo_row = (int)lane * 64;
    u64 sup = ((u64)shi << 32) | slo;
    u64 rmask;
    if (lo_row + 63 <= (int)Rv) rmask = ~0ull;
    else if (lo_row > (int)Rv)  rmask = 0ull;
    else                        rmask = (1ull << ((int)Rv - lo_row + 1)) - 1ull;
    s_kept[lane] = (~sup) & rmask;
  }
  __syncthreads();

  // zero-fill this image's output (d_out is poisoned before every launch)
  for (int x = t; x < POSTN*5; x += 1024) out[(size_t)b*POSTN*5 + x] = 0.0f;
  for (int x = t; x < POSTN;   x += 1024) out[(size_t)NB*POSTN*5 + b*POSTN + x] = 0.0f;
  if (t < 32) pref[t] = (u32)__popcll(s_kept[t]);
  __syncthreads();
  if (t == 0){
    u32 run = 0;
    for (int w = 0; w < 32; ++w){ u32 tv = pref[w]; pref[w] = run; run += tv; }
  }
  __syncthreads();
  for (int i = t; i < NCAND; i += 1024){
    u64 kw = s_kept[i >> 6];
    if ((kw >> (i & 63)) & 1ull){
      u32 rank = pref[i >> 6] + (u32)__popcll(kw & ((1ull << (i & 63)) - 1ull));
      if (rank < POSTN){
        const float* bp = sbox + ((size_t)(b*NCAND + i))*5;
        float* op = out + ((size_t)(b*POSTN + rank))*5;
        op[0]=bp[0]; op[1]=bp[1]; op[2]=bp[2]; op[3]=bp[3]; op[4]=bp[4];
        out[(size_t)NB*POSTN*5 + b*POSTN + rank] = sscore[b*NCAND + i];
      }
    }
  }
}

// ---------------------------------------------------------------------------
extern "C" void kernel_launch(void* const* d_in, const int* in_sizes, int n_in,
                              void* d_out, int out_size, void* d_ws, size_t ws_size,
                              hipStream_t stream)
{
  (void)out_size; (void)ws_size;
  const float *obj[4] = {nullptr,nullptr,nullptr,nullptr};
  const float *dlt[4] = {nullptr,nullptr,nullptr,nullptr};
  const float *anchors = nullptr;
  for (int i = 0; i < n_in; ++i){
    int s = in_sizes[i];
    const float* p = (const float*)d_in[i];
    switch (s){
      case 786432:  obj[0] = p; break;
      case 4718592: dlt[0] = p; break;
      case 196608:  obj[1] = p; break;
      case 1179648: dlt[1] = p; break;
      case 49152:   obj[2] = p; break;
      case 294912:  dlt[2] = p; break;
      case 12288:   obj[3] = p; break;
      case 73728:   dlt[3] = p; break;
      case 5222400: anchors = p; break;
      default: break;
    }
  }

  char* wsb = (char*)d_ws;
  size_t off = 0;
  auto alloc = [&](size_t bytes)->void*{
    size_t cur = (off + 255) & ~(size_t)255;
    off = cur + bytes;
    return (void*)(wsb + cur);
  };
  int*   cand_j = (int*)  alloc(16*KSEL*sizeof(int));
  float* cscore = (float*)alloc((size_t)NB*NCAND*sizeof(float));
  u32*   csmono = (u32*)  alloc((size_t)NB*NCAND*sizeof(u32));
  u64*   ctb    = (u64*)  alloc((size_t)NB*NCAND*sizeof(u64));
  float* cbox   = (float*)alloc((size_t)NB*NCAND*5*sizeof(float));
  u8*    cvalid = (u8*)   alloc((size_t)NB*NCAND);
  float* sscore = (float*)alloc((size_t)NB*NCAND*sizeof(float));
  float* sbox   = (float*)alloc((size_t)NB*NCAND*5*sizeof(float));
  u8*    svalid = (u8*)   alloc((size_t)NB*NCAND);
  float* geom   = (float*)alloc((size_t)NB*NCAND*16*sizeof(float));
  u64*   maskp  = (u64*)  alloc((size_t)NB*NCAND*32*sizeof(u64));

  hipLaunchKernelGGL(k1_topk, dim3(16), dim3(1024), 0, stream,
                     obj[0], obj[1], obj[2], obj[3], cand_j);
  hipLaunchKernelGGL(k2_decode, dim3(32), dim3(256), 0, stream,
                     obj[0], obj[1], obj[2], obj[3],
                     dlt[0], dlt[1], dlt[2], dlt[3],
                     anchors, cand_j, cscore, csmono, ctb, cbox, cvalid);
  hipLaunchKernelGGL(k3_sort, dim3(4), dim3(1024), 0, stream,
                     csmono, ctb, cscore, cbox, cvalid, sscore, sbox, geom, svalid);
  hipLaunchKernelGGL(k4_mask, dim3(65536), dim3(256), 0, stream, geom, maskp);
  hipLaunchKernelGGL(k5_nms_out, dim3(4), dim3(1024), 0, stream,
                     maskp, svalid, sbox, sscore, (float*)d_out);
}